// Round 1
// baseline (371.530 us; speedup 1.0000x reference)
//
#include <hip/hip_runtime.h>
#include <hip/hip_bf16.h>

#define FEATS 1024
#define NH 16
#define HD 64
#define SEQ 2048
#define BATCH 2
#define MTOT (BATCH*SEQ)   // 4096
#define MLPH 4096

typedef __attribute__((ext_vector_type(8))) short bf16x8;   // 8 bf16 (4 VGPRs)
typedef __attribute__((ext_vector_type(4))) float f32x4;

static_assert(sizeof(bf16x8) == 16, "bf16x8 must be 16B");

__device__ __forceinline__ unsigned short f2bf(float f) {
    unsigned int u = __float_as_uint(f);
    unsigned int lsb = (u >> 16) & 1u;
    u += 0x7fffu + lsb;              // round-to-nearest-even
    return (unsigned short)(u >> 16);
}

// ---------------------------------------------------------------- converts
__global__ __launch_bounds__(256) void cvt_kernel(const float* __restrict__ src,
                                                  unsigned short* __restrict__ dst, int n) {
    int i = (blockIdx.x * 256 + threadIdx.x) * 4;
    if (i + 3 < n) {
        float4 v = *(const float4*)(src + i);
        ushort4 o;
        o.x = f2bf(v.x); o.y = f2bf(v.y); o.z = f2bf(v.z); o.w = f2bf(v.w);
        *(ushort4*)(dst + i) = o;
    }
}

__global__ __launch_bounds__(256) void concat3_kernel(const float* __restrict__ a,
                                                      const float* __restrict__ b,
                                                      const float* __restrict__ c,
                                                      float* __restrict__ o) {
    int i = blockIdx.x * 256 + threadIdx.x;   // 3072 total
    float v = (i < 1024) ? a[i] : ((i < 2048) ? b[i - 1024] : c[i - 2048]);
    o[i] = v;
}

// ---------------------------------------------------------------- layernorm
// one block per row (FEATS=1024, 256 thr x float4)
__global__ __launch_bounds__(256) void ln_kernel(const float* __restrict__ x,
                                                 const float* __restrict__ g,
                                                 const float* __restrict__ bta,
                                                 unsigned short* __restrict__ h) {
    __shared__ float red[8];
    const int row = blockIdx.x;
    const int t = threadIdx.x;
    const float* xr = x + (size_t)row * FEATS;
    float4 v = ((const float4*)xr)[t];
    float s  = v.x + v.y + v.z + v.w;
    float ss = v.x * v.x + v.y * v.y + v.z * v.z + v.w * v.w;
#pragma unroll
    for (int off = 1; off < 64; off <<= 1) {
        s  += __shfl_xor(s, off);
        ss += __shfl_xor(ss, off);
    }
    const int w = t >> 6;
    if ((t & 63) == 0) { red[w] = s; red[4 + w] = ss; }
    __syncthreads();
    s  = red[0] + red[1] + red[2] + red[3];
    ss = red[4] + red[5] + red[6] + red[7];
    const float mu  = s * (1.f / FEATS);
    const float var = ss * (1.f / FEATS) - mu * mu;
    const float rs  = rsqrtf(var + 1e-5f);
    float4 gv = ((const float4*)g)[t];
    float4 bv = ((const float4*)bta)[t];
    ushort4 ov;
    ov.x = f2bf((v.x - mu) * rs * gv.x + bv.x);
    ov.y = f2bf((v.y - mu) * rs * gv.y + bv.y);
    ov.z = f2bf((v.z - mu) * rs * gv.z + bv.z);
    ov.w = f2bf((v.w - mu) * rs * gv.w + bv.w);
    ((ushort4*)h)[(size_t)row * (FEATS / 4) + t] = ov;
}

// ---------------------------------------------------------------- GEMM
// C[M,N] = epilogue(A[M,K] @ W[N,K]^T + bias)   bf16 in, fp32 acc
// 128x128 tile, BK=32, 4 waves each 64x64 (4x4 16x16 frags)
template <bool RELU, bool ADD, bool OUTBF16>
__global__ __launch_bounds__(256, 2)
void gemm_kernel(const unsigned short* __restrict__ A,
                 const unsigned short* __restrict__ W,
                 const float* __restrict__ bias,
                 const float* __restrict__ addend,
                 void* __restrict__ outp,
                 int M, int N, int K) {
    constexpr int BK = 32;
    constexpr int LDA = BK + 8;   // pad 16B: kills stride-64B bank conflicts
    __shared__ unsigned short Al[128 * LDA];
    __shared__ unsigned short Bl[128 * LDA];

    const int t = threadIdx.x;
    const int w = t >> 6, lane = t & 63;
    const int wr = w >> 1, wc = w & 1;
    const int li = lane & 15, lj = lane >> 4;
    const int mb = blockIdx.y * 128, nb = blockIdx.x * 128;

    const int r0 = t >> 2;             // 0..63
    const int c0 = (t & 3) * 8;        // 0,8,16,24

    f32x4 acc[4][4] = {};

    for (int k0 = 0; k0 < K; k0 += BK) {
        bf16x8 a0 = *(const bf16x8*)(A + (size_t)(mb + r0) * K + k0 + c0);
        bf16x8 a1 = *(const bf16x8*)(A + (size_t)(mb + r0 + 64) * K + k0 + c0);
        bf16x8 b0 = *(const bf16x8*)(W + (size_t)(nb + r0) * K + k0 + c0);
        bf16x8 b1 = *(const bf16x8*)(W + (size_t)(nb + r0 + 64) * K + k0 + c0);
        __syncthreads();
        *(bf16x8*)(Al + r0 * LDA + c0)        = a0;
        *(bf16x8*)(Al + (r0 + 64) * LDA + c0) = a1;
        *(bf16x8*)(Bl + r0 * LDA + c0)        = b0;
        *(bf16x8*)(Bl + (r0 + 64) * LDA + c0) = b1;
        __syncthreads();

        bf16x8 af[4], bfr[4];
#pragma unroll
        for (int m = 0; m < 4; m++)
            af[m] = *(const bf16x8*)(Al + (wr * 64 + m * 16 + li) * LDA + lj * 8);
#pragma unroll
        for (int n = 0; n < 4; n++)
            bfr[n] = *(const bf16x8*)(Bl + (wc * 64 + n * 16 + li) * LDA + lj * 8);
#pragma unroll
        for (int m = 0; m < 4; m++)
#pragma unroll
            for (int n = 0; n < 4; n++)
                acc[m][n] = __builtin_amdgcn_mfma_f32_16x16x32_bf16(af[m], bfr[n], acc[m][n], 0, 0, 0);
    }

#pragma unroll
    for (int m = 0; m < 4; m++) {
#pragma unroll
        for (int n = 0; n < 4; n++) {
            const int col = nb + wc * 64 + n * 16 + li;
            const float bv = bias[col];
#pragma unroll
            for (int r = 0; r < 4; r++) {
                const int row = mb + wr * 64 + m * 16 + lj * 4 + r;
                float v = acc[m][n][r] + bv;
                if (RELU) v = fmaxf(v, 0.f);
                if (ADD)  v += addend[(size_t)row * N + col];
                if (OUTBF16)
                    ((unsigned short*)outp)[(size_t)row * N + col] = f2bf(v);
                else
                    ((float*)outp)[(size_t)row * N + col] = v;
            }
        }
    }
}

// ---------------------------------------------------------------- attention
// flash-style. grid (B*NH, SEQ/128); 4 waves, each 32 q-rows. KV tile = 64.
__global__ __launch_bounds__(256, 2)
void attn_kernel(const unsigned short* __restrict__ qkv, unsigned short* __restrict__ out) {
    constexpr int LKV = HD + 8;   // 72 shorts, 144 B row
    __shared__ unsigned short Kl[64 * LKV];       // [key][d]
    __shared__ unsigned short Vt[HD * LKV];       // [d][key]
    __shared__ unsigned short Pl[4][32 * LKV];    // per-wave P [q][key]

    const int bh = blockIdx.x;
    const int b = bh >> 4, hh = bh & 15;
    const int q0 = blockIdx.y * 128;
    const int t = threadIdx.x, w = t >> 6, lane = t & 63;
    const int li = lane & 15, lj = lane >> 4;

    const size_t rstr = 3 * FEATS;  // 3072
    const unsigned short* qbase = qkv + (size_t)(b * SEQ) * rstr + hh * HD;

    // Q fragments stay in registers
    bf16x8 aq[2][2];
#pragma unroll
    for (int m = 0; m < 2; m++)
#pragma unroll
        for (int kk = 0; kk < 2; kk++)
            aq[m][kk] = *(const bf16x8*)(qbase + (size_t)(q0 + w * 32 + m * 16 + li) * rstr + kk * 32 + lj * 8);

    f32x4 o[2][4] = {};
    float stm[2][4], stl[2][4];
#pragma unroll
    for (int m = 0; m < 2; m++)
#pragma unroll
        for (int r = 0; r < 4; r++) { stm[m][r] = -1e30f; stl[m][r] = 0.f; }

    const float c2 = 1.4426950408889634f / 32.0f;  // log2(e)/sqrt(FEATS)

    for (int kv0 = 0; kv0 < SEQ; kv0 += 64) {
        __syncthreads();   // prior iteration's LDS reads complete
#pragma unroll
        for (int i = 0; i < 2; i++) {
            int seg = t + i * 256;                   // 0..511
            int r = seg >> 3, cs = (seg & 7) * 8;
            const unsigned short* ksrc = qbase + (size_t)(kv0 + r) * rstr + FEATS + cs;
            bf16x8 kvv = *(const bf16x8*)ksrc;
            *(bf16x8*)(Kl + r * LKV + cs) = kvv;
            const unsigned short* vsrc = qbase + (size_t)(kv0 + r) * rstr + 2 * FEATS + cs;
            bf16x8 vv = *(const bf16x8*)vsrc;
#pragma unroll
            for (int j = 0; j < 8; j++)
                Vt[(cs + j) * LKV + r] = (unsigned short)vv[j];
        }
        __syncthreads();

        // S = Q K^T  (per wave: 32q x 64k)
        f32x4 s[2][4];
#pragma unroll
        for (int n = 0; n < 4; n++) {
            bf16x8 bk0 = *(const bf16x8*)(Kl + (n * 16 + li) * LKV + lj * 8);
            bf16x8 bk1 = *(const bf16x8*)(Kl + (n * 16 + li) * LKV + 32 + lj * 8);
#pragma unroll
            for (int m = 0; m < 2; m++) {
                f32x4 acc = {};
                acc = __builtin_amdgcn_mfma_f32_16x16x32_bf16(aq[m][0], bk0, acc, 0, 0, 0);
                acc = __builtin_amdgcn_mfma_f32_16x16x32_bf16(aq[m][1], bk1, acc, 0, 0, 0);
                s[m][n] = acc;
            }
        }

        // online softmax (scores are raw; scale folded into exp2 constant)
#pragma unroll
        for (int m = 0; m < 2; m++) {
            float alpha[4];
#pragma unroll
            for (int r = 0; r < 4; r++) {
                float mx = fmaxf(fmaxf(s[m][0][r], s[m][1][r]), fmaxf(s[m][2][r], s[m][3][r]));
                mx = fmaxf(mx, __shfl_xor(mx, 1));
                mx = fmaxf(mx, __shfl_xor(mx, 2));
                mx = fmaxf(mx, __shfl_xor(mx, 4));
                mx = fmaxf(mx, __shfl_xor(mx, 8));
                const float mnew = fmaxf(stm[m][r], mx);
                alpha[r] = exp2f((stm[m][r] - mnew) * c2);
                stm[m][r] = mnew;
                float rs = 0.f;
#pragma unroll
                for (int n = 0; n < 4; n++) {
                    float p = exp2f((s[m][n][r] - mnew) * c2);
                    s[m][n][r] = p;
                    rs += p;
                }
                rs += __shfl_xor(rs, 1);
                rs += __shfl_xor(rs, 2);
                rs += __shfl_xor(rs, 4);
                rs += __shfl_xor(rs, 8);
                stl[m][r] = stl[m][r] * alpha[r] + rs;
            }
            // P -> LDS (bf16), O *= alpha
#pragma unroll
            for (int n = 0; n < 4; n++)
#pragma unroll
                for (int r = 0; r < 4; r++)
                    Pl[w][(m * 16 + lj * 4 + r) * LKV + n * 16 + li] = f2bf(s[m][n][r]);
#pragma unroll
            for (int n = 0; n < 4; n++)
#pragma unroll
                for (int r = 0; r < 4; r++)
                    o[m][n][r] *= alpha[r];
        }

        // O += P V   (K-dim = 64 keys)
#pragma unroll
        for (int kk = 0; kk < 2; kk++) {
            bf16x8 ap0 = *(const bf16x8*)(Pl[w] + (li) * LKV + kk * 32 + lj * 8);
            bf16x8 ap1 = *(const bf16x8*)(Pl[w] + (16 + li) * LKV + kk * 32 + lj * 8);
#pragma unroll
            for (int n = 0; n < 4; n++) {
                bf16x8 bv = *(const bf16x8*)(Vt + (n * 16 + li) * LKV + kk * 32 + lj * 8);
                o[0][n] = __builtin_amdgcn_mfma_f32_16x16x32_bf16(ap0, bv, o[0][n], 0, 0, 0);
                o[1][n] = __builtin_amdgcn_mfma_f32_16x16x32_bf16(ap1, bv, o[1][n], 0, 0, 0);
            }
        }
    }

    // epilogue: out[b*SEQ+row][hh*64+d] layout (b,i,h,d)
    unsigned short* ob = out + (size_t)(b * SEQ) * FEATS + hh * HD;
#pragma unroll
    for (int m = 0; m < 2; m++)
#pragma unroll
        for (int r = 0; r < 4; r++) {
            const float inv = 1.f / stl[m][r];
            const int row = q0 + w * 32 + m * 16 + lj * 4 + r;
#pragma unroll
            for (int n = 0; n < 4; n++)
                ob[(size_t)row * FEATS + n * 16 + li] = f2bf(o[m][n][r] * inv);
        }
}

// ---------------------------------------------------------------- launch
extern "C" void kernel_launch(void* const* d_in, const int* in_sizes, int n_in,
                              void* d_out, int out_size, void* d_ws, size_t ws_size,
                              hipStream_t stream) {
    const float* x     = (const float*)d_in[0];
    const float* ln1_g = (const float*)d_in[1];
    const float* ln1_b = (const float*)d_in[2];
    const float* wq    = (const float*)d_in[3];
    const float* bq    = (const float*)d_in[4];
    const float* wk    = (const float*)d_in[5];
    const float* bk    = (const float*)d_in[6];
    const float* wv    = (const float*)d_in[7];
    const float* bvv   = (const float*)d_in[8];
    const float* wo    = (const float*)d_in[9];
    const float* bo    = (const float*)d_in[10];
    const float* ln2_g = (const float*)d_in[11];
    const float* ln2_b = (const float*)d_in[12];
    const float* w1    = (const float*)d_in[13];
    const float* b1    = (const float*)d_in[14];
    const float* w2    = (const float*)d_in[15];
    const float* b2    = (const float*)d_in[16];

    // ---- workspace layout (~81 MB) ----
    unsigned short* wqkv_b = (unsigned short*)d_ws;                 // 3072*1024
    unsigned short* wo_b   = wqkv_b + 3072 * 1024;                  // 1024*1024
    unsigned short* w1_b   = wo_b + 1024 * 1024;                    // 4096*1024
    unsigned short* w2_b   = w1_b + 4096 * 1024;                    // 1024*4096
    float*          bqkv   = (float*)(w2_b + 1024 * 4096);          // 3072
    unsigned short* region = (unsigned short*)(bqkv + 3072);
    unsigned short* qkvb   = region;                                // 4096*3072
    unsigned short* hb     = region + (size_t)4096 * 3072;          // 4096*1024
    unsigned short* a1     = region;                                // 4096*4096 (aliases qkv+h, both dead)
    unsigned short* attn_o = region + (size_t)4096 * 4096;          // 4096*1024
    unsigned short* h2     = attn_o;                                // alias (attn_o dead when written)
    float*          out1   = (float*)(attn_o + (size_t)4096 * 1024);// 4096*1024 fp32
    float*          outf   = (float*)d_out;

    dim3 blk(256);

    // weight converts (fp32 -> bf16)
    cvt_kernel<<<1024, blk, 0, stream>>>(wq, wqkv_b, 1024 * 1024);
    cvt_kernel<<<1024, blk, 0, stream>>>(wk, wqkv_b + 1024 * 1024, 1024 * 1024);
    cvt_kernel<<<1024, blk, 0, stream>>>(wv, wqkv_b + 2 * 1024 * 1024, 1024 * 1024);
    cvt_kernel<<<1024, blk, 0, stream>>>(wo, wo_b, 1024 * 1024);
    cvt_kernel<<<4096, blk, 0, stream>>>(w1, w1_b, 4096 * 1024);
    cvt_kernel<<<4096, blk, 0, stream>>>(w2, w2_b, 4096 * 1024);
    concat3_kernel<<<12, blk, 0, stream>>>(bq, bk, bvv, bqkv);

    // LN1 -> h (bf16)
    ln_kernel<<<MTOT, blk, 0, stream>>>(x, ln1_g, ln1_b, hb);

    // fused QKV gemm: (4096,1024) @ (3072,1024)^T -> (4096,3072)
    gemm_kernel<false, false, true><<<dim3(3072 / 128, MTOT / 128), blk, 0, stream>>>(
        hb, wqkv_b, bqkv, nullptr, qkvb, MTOT, 3072, FEATS);

    // attention
    attn_kernel<<<dim3(BATCH * NH, SEQ / 128), blk, 0, stream>>>(qkvb, attn_o);

    // out proj + residual: out1 = attn @ wo^T + bo + x   (fp32)
    gemm_kernel<false, true, false><<<dim3(1024 / 128, MTOT / 128), blk, 0, stream>>>(
        attn_o, wo_b, bo, x, out1, MTOT, FEATS, FEATS);

    // LN2 -> h2 (bf16)
    ln_kernel<<<MTOT, blk, 0, stream>>>(out1, ln2_g, ln2_b, h2);

    // MLP1: relu(h2 @ w1^T + b1) -> a1 (bf16)
    gemm_kernel<true, false, true><<<dim3(MLPH / 128, MTOT / 128), blk, 0, stream>>>(
        h2, w1_b, b1, nullptr, a1, MTOT, MLPH, FEATS);

    // MLP2: relu(a1 @ w2^T + b2) + out1 -> out (fp32)
    gemm_kernel<true, true, false><<<dim3(1024 / 128, MTOT / 128), blk, 0, stream>>>(
        a1, w2_b, b2, out1, outf, MTOT, FEATS, MLPH);
}

// Round 2
// 304.091 us; speedup vs baseline: 1.2218x; 1.2218x over previous
//
#include <hip/hip_runtime.h>
#include <hip/hip_bf16.h>

#define FEATS 1024
#define NH 16
#define HD 64
#define SEQ 2048
#define BATCH 2
#define MTOT (BATCH*SEQ)   // 4096
#define MLPH 4096

typedef __attribute__((ext_vector_type(8))) short bf16x8;   // 8 bf16 (4 VGPRs)
typedef __attribute__((ext_vector_type(4))) float f32x4;
typedef unsigned short ushort_t;

static_assert(sizeof(bf16x8) == 16, "bf16x8 must be 16B");

__device__ __forceinline__ unsigned short f2bf(float f) {
    unsigned int u = __float_as_uint(f);
    unsigned int lsb = (u >> 16) & 1u;
    u += 0x7fffu + lsb;              // round-to-nearest-even
    return (unsigned short)(u >> 16);
}

// async global->LDS, 16B per lane. Dest must be wave-uniform base + lane*16.
#define ASYNC16(GP, LP) __builtin_amdgcn_global_load_lds( \
    (const __attribute__((address_space(1))) void*)(GP),  \
    (__attribute__((address_space(3))) void*)(LP), 16, 0, 0)

// ---------------------------------------------------------------- converts
__global__ __launch_bounds__(256) void cvt_kernel(const float* __restrict__ src,
                                                  unsigned short* __restrict__ dst, int n) {
    int i = (blockIdx.x * 256 + threadIdx.x) * 4;
    if (i + 3 < n) {
        float4 v = *(const float4*)(src + i);
        ushort4 o;
        o.x = f2bf(v.x); o.y = f2bf(v.y); o.z = f2bf(v.z); o.w = f2bf(v.w);
        *(ushort4*)(dst + i) = o;
    }
}

__global__ __launch_bounds__(256) void concat3_kernel(const float* __restrict__ a,
                                                      const float* __restrict__ b,
                                                      const float* __restrict__ c,
                                                      float* __restrict__ o) {
    int i = blockIdx.x * 256 + threadIdx.x;   // 3072 total
    float v = (i < 1024) ? a[i] : ((i < 2048) ? b[i - 1024] : c[i - 2048]);
    o[i] = v;
}

// ---------------------------------------------------------------- layernorm
__global__ __launch_bounds__(256) void ln_kernel(const float* __restrict__ x,
                                                 const float* __restrict__ g,
                                                 const float* __restrict__ bta,
                                                 unsigned short* __restrict__ h) {
    __shared__ float red[8];
    const int row = blockIdx.x;
    const int t = threadIdx.x;
    const float* xr = x + (size_t)row * FEATS;
    float4 v = ((const float4*)xr)[t];
    float s  = v.x + v.y + v.z + v.w;
    float ss = v.x * v.x + v.y * v.y + v.z * v.z + v.w * v.w;
#pragma unroll
    for (int off = 1; off < 64; off <<= 1) {
        s  += __shfl_xor(s, off);
        ss += __shfl_xor(ss, off);
    }
    const int w = t >> 6;
    if ((t & 63) == 0) { red[w] = s; red[4 + w] = ss; }
    __syncthreads();
    s  = red[0] + red[1] + red[2] + red[3];
    ss = red[4] + red[5] + red[6] + red[7];
    const float mu  = s * (1.f / FEATS);
    const float var = ss * (1.f / FEATS) - mu * mu;
    const float rs  = rsqrtf(var + 1e-5f);
    float4 gv = ((const float4*)g)[t];
    float4 bv = ((const float4*)bta)[t];
    ushort4 ov;
    ov.x = f2bf((v.x - mu) * rs * gv.x + bv.x);
    ov.y = f2bf((v.y - mu) * rs * gv.y + bv.y);
    ov.z = f2bf((v.z - mu) * rs * gv.z + bv.z);
    ov.w = f2bf((v.w - mu) * rs * gv.w + bv.w);
    ((ushort4*)h)[(size_t)row * (FEATS / 4) + t] = ov;
}

// ---------------------------------------------------------------- GEMM (m97 recipe)
// C[M,N] = epilogue(A[M,K] @ W[N,K]^T + bias); 128x128 tile, BK=32,
// global_load_lds width-16 staging into linear [128][32] LDS.
template <bool RELU, bool ADD, bool OUTBF16>
__global__ __launch_bounds__(256, 2)
void gemm_kernel(const unsigned short* __restrict__ A,
                 const unsigned short* __restrict__ W,
                 const float* __restrict__ bias,
                 const float* __restrict__ addend,
                 void* __restrict__ outp,
                 int M, int N, int K) {
    __shared__ unsigned short Al[128 * 32];
    __shared__ unsigned short Bl[128 * 32];

    const int t = threadIdx.x;
    const int w = t >> 6, lane = t & 63;
    const int wr = w >> 1, wc = w & 1;
    const int li = lane & 15, lj = lane >> 4;
    const int mb = blockIdx.y * 128, nb = blockIdx.x * 128;

    // staging: issue i covers rows (i*4+w)*16 .. +15; lane -> row (lane>>2), chunk lane&3
    const int srow = lane >> 2, sc = (lane & 3) * 8;
    const unsigned short* gA0 = A + (size_t)(mb + w * 16 + srow) * K + sc;
    const unsigned short* gA1 = gA0 + (size_t)64 * K;
    const unsigned short* gB0 = W + (size_t)(nb + w * 16 + srow) * K + sc;
    const unsigned short* gB1 = gB0 + (size_t)64 * K;
    unsigned short* lA0 = Al + (size_t)w * 512 + (size_t)lane * 8;
    unsigned short* lA1 = lA0 + 2048;
    unsigned short* lB0 = Bl + (size_t)w * 512 + (size_t)lane * 8;
    unsigned short* lB1 = lB0 + 2048;

    f32x4 acc[4][4] = {};

    for (int k0 = 0; k0 < K; k0 += 32) {
        __syncthreads();                 // prior tile's ds_reads complete
        ASYNC16(gA0 + k0, lA0);
        ASYNC16(gA1 + k0, lA1);
        ASYNC16(gB0 + k0, lB0);
        ASYNC16(gB1 + k0, lB1);
        __syncthreads();                 // vmcnt(0) drain -> tile ready

        bf16x8 af[4], bfr[4];
#pragma unroll
        for (int m = 0; m < 4; m++)
            af[m] = *(const bf16x8*)(Al + (wr * 64 + m * 16 + li) * 32 + lj * 8);
#pragma unroll
        for (int n = 0; n < 4; n++)
            bfr[n] = *(const bf16x8*)(Bl + (wc * 64 + n * 16 + li) * 32 + lj * 8);
#pragma unroll
        for (int m = 0; m < 4; m++)
#pragma unroll
            for (int n = 0; n < 4; n++)
                acc[m][n] = __builtin_amdgcn_mfma_f32_16x16x32_bf16(af[m], bfr[n], acc[m][n], 0, 0, 0);
    }

#pragma unroll
    for (int m = 0; m < 4; m++) {
#pragma unroll
        for (int n = 0; n < 4; n++) {
            const int col = nb + wc * 64 + n * 16 + li;
            const float bv = bias[col];
#pragma unroll
            for (int r = 0; r < 4; r++) {
                const int row = mb + wr * 64 + m * 16 + lj * 4 + r;
                float v = acc[m][n][r] + bv;
                if (RELU) v = fmaxf(v, 0.f);
                if (ADD)  v += addend[(size_t)row * N + col];
                if (OUTBF16)
                    ((unsigned short*)outp)[(size_t)row * N + col] = f2bf(v);
                else
                    ((float*)outp)[(size_t)row * N + col] = v;
            }
        }
    }
}

// ---------------------------------------------------------------- V transpose
// vt[bh][d][seq] <- qkv V part. LDS-tiled, coalesced both sides.
__global__ __launch_bounds__(256) void vtrans_kernel(const unsigned short* __restrict__ qkv,
                                                     unsigned short* __restrict__ vt) {
    constexpr int LDV = 68;
    __shared__ unsigned short Vl[64 * LDV];
    const int bh = blockIdx.x, st = blockIdx.y;
    const int b = bh >> 4, h = bh & 15;
    const int t = threadIdx.x;
    const unsigned short* src = qkv + (size_t)(b * SEQ + st * 64) * (3 * FEATS) + 2 * FEATS + h * HD;
#pragma unroll
    for (int i = 0; i < 2; i++) {
        int idx = t + i * 256;
        int r = idx >> 3, c = (idx & 7) * 8;
        *(bf16x8*)(Vl + r * LDV + c) = *(const bf16x8*)(src + (size_t)r * (3 * FEATS) + c);
    }
    __syncthreads();
    unsigned short* dst = vt + (size_t)bh * HD * SEQ + st * 64;
#pragma unroll
    for (int i = 0; i < 2; i++) {
        int idx = t + i * 256;
        int d = idx >> 3, s8 = (idx & 7) * 8;
        bf16x8 v;
#pragma unroll
        for (int j = 0; j < 8; j++) v[j] = Vl[(s8 + j) * LDV + d];
        *(bf16x8*)(dst + (size_t)d * SEQ + s8) = v;
    }
}

// ---------------------------------------------------------------- attention
// 512 thr (8 waves x 16 q-rows), KV tile 64. No max-subtraction (scores
// bounded ~|4| after scale), denominator reduced once at the end.
__global__ __launch_bounds__(512, 2)
void attn_kernel(const unsigned short* __restrict__ qkv,
                 const unsigned short* __restrict__ vt,
                 unsigned short* __restrict__ out) {
    constexpr int LK = 72;   // K / V^T LDS pad (16B-aligned rows, bank-balanced)
    constexpr int LP = 68;   // P LDS pad
    __shared__ unsigned short Kl[64 * LK];
    __shared__ unsigned short Vtl[64 * LK];
    __shared__ unsigned short Pl[8][16 * LP];

    const int bh = blockIdx.x;
    const int b = bh >> 4, h = bh & 15;
    const int q0 = blockIdx.y * 128;
    const int t = threadIdx.x, w = t >> 6, lane = t & 63;
    const int li = lane & 15, lj = lane >> 4;

    const size_t rstr = 3 * FEATS;
    const unsigned short* qkvb = qkv + (size_t)(b * SEQ) * rstr;
    const unsigned short* ksrc = qkvb + FEATS + h * HD;
    const unsigned short* vsrc = vt + (size_t)bh * HD * SEQ;

    // Q fragments in registers (wave's 16 q-rows)
    bf16x8 aq[2];
#pragma unroll
    for (int kk = 0; kk < 2; kk++)
        aq[kk] = *(const bf16x8*)(qkvb + (size_t)(q0 + w * 16 + li) * rstr + h * HD + kk * 32 + lj * 8);

    f32x4 o[4] = {};
    float lsum[4] = {0.f, 0.f, 0.f, 0.f};
    const float c2 = 1.4426950408889634f / 32.0f;  // log2(e)/sqrt(FEATS)

    const int sr = t >> 3, scol = (t & 7) * 8;     // staging coords (512 thr)

    for (int kv0 = 0; kv0 < SEQ; kv0 += 64) {
        __syncthreads();
        *(bf16x8*)(Kl + sr * LK + scol) =
            *(const bf16x8*)(ksrc + (size_t)(kv0 + sr) * rstr + scol);
        *(bf16x8*)(Vtl + sr * LK + scol) =
            *(const bf16x8*)(vsrc + (size_t)sr * SEQ + kv0 + scol);
        __syncthreads();

        // S = Q K^T : per wave 16q x 64k
        f32x4 s[4];
#pragma unroll
        for (int n = 0; n < 4; n++) {
            bf16x8 b0 = *(const bf16x8*)(Kl + (n * 16 + li) * LK + lj * 8);
            bf16x8 b1 = *(const bf16x8*)(Kl + (n * 16 + li) * LK + 32 + lj * 8);
            f32x4 acc = {};
            acc = __builtin_amdgcn_mfma_f32_16x16x32_bf16(aq[0], b0, acc, 0, 0, 0);
            acc = __builtin_amdgcn_mfma_f32_16x16x32_bf16(aq[1], b1, acc, 0, 0, 0);
            s[n] = acc;
        }

        // p = exp(s/32), per-lane partial denominator, P -> LDS bf16
#pragma unroll
        for (int n = 0; n < 4; n++)
#pragma unroll
            for (int r = 0; r < 4; r++) {
                float p = exp2f(s[n][r] * c2);
                lsum[r] += p;
                Pl[w][(lj * 4 + r) * LP + n * 16 + li] = f2bf(p);
            }

        // O += P V
#pragma unroll
        for (int kk = 0; kk < 2; kk++) {
            bf16x8 ap = *(const bf16x8*)(Pl[w] + li * LP + kk * 32 + lj * 8);
#pragma unroll
            for (int n = 0; n < 4; n++) {
                bf16x8 bv = *(const bf16x8*)(Vtl + (n * 16 + li) * LK + kk * 32 + lj * 8);
                o[n] = __builtin_amdgcn_mfma_f32_16x16x32_bf16(ap, bv, o[n], 0, 0, 0);
            }
        }
    }

    // final denominator reduce (over li lanes) + output
    float inv[4];
#pragma unroll
    for (int r = 0; r < 4; r++) {
        float s = lsum[r];
        s += __shfl_xor(s, 1);
        s += __shfl_xor(s, 2);
        s += __shfl_xor(s, 4);
        s += __shfl_xor(s, 8);
        inv[r] = 1.f / s;
    }
    unsigned short* ob = out + (size_t)(b * SEQ + q0 + w * 16) * FEATS + h * HD;
#pragma unroll
    for (int n = 0; n < 4; n++)
#pragma unroll
        for (int r = 0; r < 4; r++)
            ob[(size_t)(lj * 4 + r) * FEATS + n * 16 + li] = f2bf(o[n][r] * inv[r]);
}

// ---------------------------------------------------------------- launch
extern "C" void kernel_launch(void* const* d_in, const int* in_sizes, int n_in,
                              void* d_out, int out_size, void* d_ws, size_t ws_size,
                              hipStream_t stream) {
    const float* x     = (const float*)d_in[0];
    const float* ln1_g = (const float*)d_in[1];
    const float* ln1_b = (const float*)d_in[2];
    const float* wq    = (const float*)d_in[3];
    const float* bq    = (const float*)d_in[4];
    const float* wk    = (const float*)d_in[5];
    const float* bk    = (const float*)d_in[6];
    const float* wv    = (const float*)d_in[7];
    const float* bvv   = (const float*)d_in[8];
    const float* wo    = (const float*)d_in[9];
    const float* bo    = (const float*)d_in[10];
    const float* ln2_g = (const float*)d_in[11];
    const float* ln2_b = (const float*)d_in[12];
    const float* w1    = (const float*)d_in[13];
    const float* b1    = (const float*)d_in[14];
    const float* w2    = (const float*)d_in[15];
    const float* b2    = (const float*)d_in[16];

    // ---- workspace layout (~84 MB) ----
    unsigned short* wqkv_b = (unsigned short*)d_ws;                 // 3072*1024
    unsigned short* wo_b   = wqkv_b + 3072 * 1024;                  // 1024*1024
    unsigned short* w1_b   = wo_b + 1024 * 1024;                    // 4096*1024
    unsigned short* w2_b   = w1_b + 4096 * 1024;                    // 1024*4096
    float*          bqkv   = (float*)(w2_b + 1024 * 4096);          // 3072
    unsigned short* region = (unsigned short*)(bqkv + 3072);
    unsigned short* qkvb   = region;                                // 4096*3072
    unsigned short* hb     = region + (size_t)4096 * 3072;          // 4096*1024 (LN1 out)
    unsigned short* vtb    = hb;                                    // 32*64*2048 (hb dead after QKV gemm)
    unsigned short* a1     = region;                                // 4096*4096 (qkv+vt dead after attn)
    unsigned short* attn_o = region + (size_t)4096 * 4096;          // 4096*1024
    unsigned short* h2     = attn_o;                                // alias (attn_o dead when written)
    float*          out1   = (float*)(attn_o + (size_t)4096 * 1024);// 4096*1024 fp32
    float*          outf   = (float*)d_out;

    dim3 blk(256);

    cvt_kernel<<<1024, blk, 0, stream>>>(wq, wqkv_b, 1024 * 1024);
    cvt_kernel<<<1024, blk, 0, stream>>>(wk, wqkv_b + 1024 * 1024, 1024 * 1024);
    cvt_kernel<<<1024, blk, 0, stream>>>(wv, wqkv_b + 2 * 1024 * 1024, 1024 * 1024);
    cvt_kernel<<<1024, blk, 0, stream>>>(wo, wo_b, 1024 * 1024);
    cvt_kernel<<<4096, blk, 0, stream>>>(w1, w1_b, 4096 * 1024);
    cvt_kernel<<<4096, blk, 0, stream>>>(w2, w2_b, 4096 * 1024);
    concat3_kernel<<<12, blk, 0, stream>>>(bq, bk, bvv, bqkv);

    ln_kernel<<<MTOT, blk, 0, stream>>>(x, ln1_g, ln1_b, hb);

    gemm_kernel<false, false, true><<<dim3(3072 / 128, MTOT / 128), blk, 0, stream>>>(
        hb, wqkv_b, bqkv, nullptr, qkvb, MTOT, 3072, FEATS);

    vtrans_kernel<<<dim3(BATCH * NH, SEQ / 64), blk, 0, stream>>>(qkvb, vtb);

    attn_kernel<<<dim3(BATCH * NH, SEQ / 128), dim3(512), 0, stream>>>(qkvb, vtb, attn_o);

    gemm_kernel<false, true, false><<<dim3(1024 / 128, MTOT / 128), blk, 0, stream>>>(
        attn_o, wo_b, bo, x, out1, MTOT, FEATS, FEATS);

    ln_kernel<<<MTOT, blk, 0, stream>>>(out1, ln2_g, ln2_b, h2);

    gemm_kernel<true, false, true><<<dim3(MLPH / 128, MTOT / 128), blk, 0, stream>>>(
        h2, w1_b, b1, nullptr, a1, MTOT, MLPH, FEATS);

    gemm_kernel<true, true, false><<<dim3(1024 / 128, MTOT / 128), blk, 0, stream>>>(
        a1, w2_b, b2, out1, outf, MTOT, FEATS, MLPH);
}

// Round 3
// 262.852 us; speedup vs baseline: 1.4135x; 1.1569x over previous
//
#include <hip/hip_runtime.h>
#include <hip/hip_bf16.h>

#define FEATS 1024
#define NH 16
#define HD 64
#define SEQ 2048
#define BATCH 2
#define MTOT (BATCH*SEQ)   // 4096
#define MLPH 4096

typedef __attribute__((ext_vector_type(8))) short bf16x8;   // 8 bf16 (4 VGPRs)
typedef __attribute__((ext_vector_type(4))) float f32x4;

static_assert(sizeof(bf16x8) == 16, "bf16x8 must be 16B");

__device__ __forceinline__ unsigned short f2bf(float f) {
    unsigned int u = __float_as_uint(f);
    unsigned int lsb = (u >> 16) & 1u;
    u += 0x7fffu + lsb;              // round-to-nearest-even
    return (unsigned short)(u >> 16);
}

// async global->LDS, 16B per lane. Dest must be wave-uniform base + lane*16.
#define ASYNC16(GP, LP) __builtin_amdgcn_global_load_lds( \
    (const __attribute__((address_space(1))) void*)(GP),  \
    (__attribute__((address_space(3))) void*)(LP), 16, 0, 0)

// ---------------------------------------------------------------- converts
__global__ __launch_bounds__(256) void cvt_kernel(const float* __restrict__ src,
                                                  unsigned short* __restrict__ dst, int n) {
    int i = (blockIdx.x * 256 + threadIdx.x) * 4;
    if (i + 3 < n) {
        float4 v = *(const float4*)(src + i);
        ushort4 o;
        o.x = f2bf(v.x); o.y = f2bf(v.y); o.z = f2bf(v.z); o.w = f2bf(v.w);
        *(ushort4*)(dst + i) = o;
    }
}

__global__ __launch_bounds__(256) void concat3_kernel(const float* __restrict__ a,
                                                      const float* __restrict__ b,
                                                      const float* __restrict__ c,
                                                      float* __restrict__ o) {
    int i = blockIdx.x * 256 + threadIdx.x;   // 3072 total
    float v = (i < 1024) ? a[i] : ((i < 2048) ? b[i - 1024] : c[i - 2048]);
    o[i] = v;
}

// ---------------------------------------------------------------- layernorm
__global__ __launch_bounds__(256) void ln_kernel(const float* __restrict__ x,
                                                 const float* __restrict__ g,
                                                 const float* __restrict__ bta,
                                                 unsigned short* __restrict__ h) {
    __shared__ float red[8];
    const int row = blockIdx.x;
    const int t = threadIdx.x;
    const float* xr = x + (size_t)row * FEATS;
    float4 v = ((const float4*)xr)[t];
    float s  = v.x + v.y + v.z + v.w;
    float ss = v.x * v.x + v.y * v.y + v.z * v.z + v.w * v.w;
#pragma unroll
    for (int off = 1; off < 64; off <<= 1) {
        s  += __shfl_xor(s, off);
        ss += __shfl_xor(ss, off);
    }
    const int w = t >> 6;
    if ((t & 63) == 0) { red[w] = s; red[4 + w] = ss; }
    __syncthreads();
    s  = red[0] + red[1] + red[2] + red[3];
    ss = red[4] + red[5] + red[6] + red[7];
    const float mu  = s * (1.f / FEATS);
    const float var = ss * (1.f / FEATS) - mu * mu;
    const float rs  = rsqrtf(var + 1e-5f);
    float4 gv = ((const float4*)g)[t];
    float4 bv = ((const float4*)bta)[t];
    ushort4 ov;
    ov.x = f2bf((v.x - mu) * rs * gv.x + bv.x);
    ov.y = f2bf((v.y - mu) * rs * gv.y + bv.y);
    ov.z = f2bf((v.z - mu) * rs * gv.z + bv.z);
    ov.w = f2bf((v.w - mu) * rs * gv.w + bv.w);
    ((ushort4*)h)[(size_t)row * (FEATS / 4) + t] = ov;
}

// ---------------------------------------------------------------- GEMM
// C[M,N] = epilogue(A[M,K] @ W[N,K]^T + bias); 128x128 tile, BK=32.
// Depth-2 pipeline: 3 LDS buffers, counted vmcnt(4), raw s_barrier (no
// __syncthreads -> no forced vmcnt(0) drain). XCD-swizzled 1-D grid.
template <bool RELU, bool ADD, bool OUTBF16>
__global__ __launch_bounds__(256, 2)
void gemm_kernel(const unsigned short* __restrict__ A,
                 const unsigned short* __restrict__ W,
                 const float* __restrict__ bias,
                 const float* __restrict__ addend,
                 void* __restrict__ outp,
                 int M, int N, int K, int gx) {
    __shared__ unsigned short lds[3][2][128 * 32];   // [buf][A=0/B=1][row*32+col]

    const int t = threadIdx.x;
    const int w = t >> 6, lane = t & 63;
    const int wr = w >> 1, wc = w & 1;
    const int li = lane & 15, lj = lane >> 4;

    // XCD-aware swizzle (all grids are multiples of 8)
    const int nwg = gridDim.x;
    const int cpx = nwg >> 3;
    const int wg = blockIdx.x;
    const int swz = (wg & 7) * cpx + (wg >> 3);
    const int mb = (swz / gx) * 128, nb = (swz % gx) * 128;

    // staging: wave w covers rows w*16..w*16+15 (and +64); lane -> (row lane>>2, col (lane&3)*8)
    const int srow = lane >> 2, sc = (lane & 3) * 8;
    const unsigned short* gA = A + (size_t)(mb + w * 16 + srow) * K + sc;
    const unsigned short* gB = W + (size_t)(nb + w * 16 + srow) * K + sc;
    const size_t half = (size_t)64 * K;
    const int lbase = w * 512 + lane * 8;

    const int nt = K >> 5;

#define STAGE(BUF, K0)                                             \
    do {                                                           \
        unsigned short* la_ = &lds[BUF][0][lbase];                 \
        unsigned short* lb_ = &lds[BUF][1][lbase];                 \
        ASYNC16(gA + (K0), la_);                                   \
        ASYNC16(gA + half + (K0), la_ + 2048);                     \
        ASYNC16(gB + (K0), lb_);                                   \
        ASYNC16(gB + half + (K0), lb_ + 2048);                     \
    } while (0)

    STAGE(0, 0);
    STAGE(1, 32);
    asm volatile("s_waitcnt vmcnt(4)" ::: "memory");   // buf0 landed, buf1 in flight
    __builtin_amdgcn_s_barrier();

    f32x4 acc[4][4] = {};

    for (int i = 0; i < nt; ++i) {
        const int cur = i % 3;
        const unsigned short* Al = &lds[cur][0][0];
        const unsigned short* Bl = &lds[cur][1][0];

        // 1) fragment ds_reads of the ready buffer (before any LDS-DMA issue)
        bf16x8 af[4], bfr[4];
#pragma unroll
        for (int m = 0; m < 4; m++)
            af[m] = *(const bf16x8*)(Al + (wr * 64 + m * 16 + li) * 32 + lj * 8);
#pragma unroll
        for (int n = 0; n < 4; n++)
            bfr[n] = *(const bf16x8*)(Bl + (wc * 64 + n * 16 + li) * 32 + lj * 8);

        // 2) prefetch tile i+2 into the buffer freed after this iteration
        const int pf = i + 2 < nt;
        if (pf) STAGE((i + 2) % 3, (i + 2) * 32);

        // 3) compute
#pragma unroll
        for (int m = 0; m < 4; m++)
#pragma unroll
            for (int n = 0; n < 4; n++)
                acc[m][n] = __builtin_amdgcn_mfma_f32_16x16x32_bf16(af[m], bfr[n], acc[m][n], 0, 0, 0);

        // 4) wait only for tile i+1 (leave i+2's 4 loads in flight), then barrier
        if (i + 1 < nt) {
            if (pf) asm volatile("s_waitcnt vmcnt(4)" ::: "memory");
            else    asm volatile("s_waitcnt vmcnt(0)" ::: "memory");
            __builtin_amdgcn_s_barrier();
        }
    }
#undef STAGE

#pragma unroll
    for (int m = 0; m < 4; m++) {
#pragma unroll
        for (int n = 0; n < 4; n++) {
            const int col = nb + wc * 64 + n * 16 + li;
            const float bv = bias[col];
#pragma unroll
            for (int r = 0; r < 4; r++) {
                const int row = mb + wr * 64 + m * 16 + lj * 4 + r;
                float v = acc[m][n][r] + bv;
                if (RELU) v = fmaxf(v, 0.f);
                if (ADD)  v += addend[(size_t)row * N + col];
                if (OUTBF16)
                    ((unsigned short*)outp)[(size_t)row * N + col] = f2bf(v);
                else
                    ((float*)outp)[(size_t)row * N + col] = v;
            }
        }
    }
}

// ---------------------------------------------------------------- V transpose
__global__ __launch_bounds__(256) void vtrans_kernel(const unsigned short* __restrict__ qkv,
                                                     unsigned short* __restrict__ vt) {
    constexpr int LDV = 68;
    __shared__ unsigned short Vl[64 * LDV];
    const int bh = blockIdx.x, st = blockIdx.y;
    const int b = bh >> 4, h = bh & 15;
    const int t = threadIdx.x;
    const unsigned short* src = qkv + (size_t)(b * SEQ + st * 64) * (3 * FEATS) + 2 * FEATS + h * HD;
#pragma unroll
    for (int i = 0; i < 2; i++) {
        int idx = t + i * 256;
        int r = idx >> 3, c = (idx & 7) * 8;
        *(bf16x8*)(Vl + r * LDV + c) = *(const bf16x8*)(src + (size_t)r * (3 * FEATS) + c);
    }
    __syncthreads();
    unsigned short* dst = vt + (size_t)bh * HD * SEQ + st * 64;
#pragma unroll
    for (int i = 0; i < 2; i++) {
        int idx = t + i * 256;
        int d = idx >> 3, s8 = (idx & 7) * 8;
        bf16x8 v;
#pragma unroll
        for (int j = 0; j < 8; j++) v[j] = Vl[(s8 + j) * LDV + d];
        *(bf16x8*)(dst + (size_t)d * SEQ + s8) = v;
    }
}

// ---------------------------------------------------------------- attention
// 512 thr (8 waves x 16 q-rows), KV tile 64. No max-subtraction (scores
// bounded after 1/sqrt(1024) scale), denominator reduced once at the end.
__global__ __launch_bounds__(512, 2)
void attn_kernel(const unsigned short* __restrict__ qkv,
                 const unsigned short* __restrict__ vt,
                 unsigned short* __restrict__ out) {
    constexpr int LK = 72;
    constexpr int LP = 68;
    __shared__ unsigned short Kl[64 * LK];
    __shared__ unsigned short Vtl[64 * LK];
    __shared__ unsigned short Pl[8][16 * LP];

    const int bh = blockIdx.x;
    const int b = bh >> 4, h = bh & 15;
    const int q0 = blockIdx.y * 128;
    const int t = threadIdx.x, w = t >> 6, lane = t & 63;
    const int li = lane & 15, lj = lane >> 4;

    const size_t rstr = 3 * FEATS;
    const unsigned short* qkvb = qkv + (size_t)(b * SEQ) * rstr;
    const unsigned short* ksrc = qkvb + FEATS + h * HD;
    const unsigned short* vsrc = vt + (size_t)bh * HD * SEQ;

    bf16x8 aq[2];
#pragma unroll
    for (int kk = 0; kk < 2; kk++)
        aq[kk] = *(const bf16x8*)(qkvb + (size_t)(q0 + w * 16 + li) * rstr + h * HD + kk * 32 + lj * 8);

    f32x4 o[4] = {};
    float lsum[4] = {0.f, 0.f, 0.f, 0.f};
    const float c2 = 1.4426950408889634f / 32.0f;  // log2(e)/sqrt(FEATS)

    const int sr = t >> 3, scol = (t & 7) * 8;

    for (int kv0 = 0; kv0 < SEQ; kv0 += 64) {
        __syncthreads();
        *(bf16x8*)(Kl + sr * LK + scol) =
            *(const bf16x8*)(ksrc + (size_t)(kv0 + sr) * rstr + scol);
        *(bf16x8*)(Vtl + sr * LK + scol) =
            *(const bf16x8*)(vsrc + (size_t)sr * SEQ + kv0 + scol);
        __syncthreads();

        f32x4 s[4];
#pragma unroll
        for (int n = 0; n < 4; n++) {
            bf16x8 b0 = *(const bf16x8*)(Kl + (n * 16 + li) * LK + lj * 8);
            bf16x8 b1 = *(const bf16x8*)(Kl + (n * 16 + li) * LK + 32 + lj * 8);
            f32x4 acc = {};
            acc = __builtin_amdgcn_mfma_f32_16x16x32_bf16(aq[0], b0, acc, 0, 0, 0);
            acc = __builtin_amdgcn_mfma_f32_16x16x32_bf16(aq[1], b1, acc, 0, 0, 0);
            s[n] = acc;
        }

#pragma unroll
        for (int n = 0; n < 4; n++)
#pragma unroll
            for (int r = 0; r < 4; r++) {
                float p = exp2f(s[n][r] * c2);
                lsum[r] += p;
                Pl[w][(lj * 4 + r) * LP + n * 16 + li] = f2bf(p);
            }

#pragma unroll
        for (int kk = 0; kk < 2; kk++) {
            bf16x8 ap = *(const bf16x8*)(Pl[w] + li * LP + kk * 32 + lj * 8);
#pragma unroll
            for (int n = 0; n < 4; n++) {
                bf16x8 bv = *(const bf16x8*)(Vtl + (n * 16 + li) * LK + kk * 32 + lj * 8);
                o[n] = __builtin_amdgcn_mfma_f32_16x16x32_bf16(ap, bv, o[n], 0, 0, 0);
            }
        }
    }

    float inv[4];
#pragma unroll
    for (int r = 0; r < 4; r++) {
        float s = lsum[r];
        s += __shfl_xor(s, 1);
        s += __shfl_xor(s, 2);
        s += __shfl_xor(s, 4);
        s += __shfl_xor(s, 8);
        inv[r] = 1.f / s;
    }
    unsigned short* ob = out + (size_t)(b * SEQ + q0 + w * 16) * FEATS + h * HD;
#pragma unroll
    for (int n = 0; n < 4; n++)
#pragma unroll
        for (int r = 0; r < 4; r++)
            ob[(size_t)(lj * 4 + r) * FEATS + n * 16 + li] = f2bf(o[n][r] * inv[r]);
}

// ---------------------------------------------------------------- launch
extern "C" void kernel_launch(void* const* d_in, const int* in_sizes, int n_in,
                              void* d_out, int out_size, void* d_ws, size_t ws_size,
                              hipStream_t stream) {
    const float* x     = (const float*)d_in[0];
    const float* ln1_g = (const float*)d_in[1];
    const float* ln1_b = (const float*)d_in[2];
    const float* wq    = (const float*)d_in[3];
    const float* bq    = (const float*)d_in[4];
    const float* wk    = (const float*)d_in[5];
    const float* bk    = (const float*)d_in[6];
    const float* wv    = (const float*)d_in[7];
    const float* bvv   = (const float*)d_in[8];
    const float* wo    = (const float*)d_in[9];
    const float* bo    = (const float*)d_in[10];
    const float* ln2_g = (const float*)d_in[11];
    const float* ln2_b = (const float*)d_in[12];
    const float* w1    = (const float*)d_in[13];
    const float* b1    = (const float*)d_in[14];
    const float* w2    = (const float*)d_in[15];
    const float* b2    = (const float*)d_in[16];

    // ---- workspace layout (~84 MB) ----
    unsigned short* wqkv_b = (unsigned short*)d_ws;                 // 3072*1024
    unsigned short* wo_b   = wqkv_b + 3072 * 1024;                  // 1024*1024
    unsigned short* w1_b   = wo_b + 1024 * 1024;                    // 4096*1024
    unsigned short* w2_b   = w1_b + 4096 * 1024;                    // 1024*4096
    float*          bqkv   = (float*)(w2_b + 1024 * 4096);          // 3072
    unsigned short* region = (unsigned short*)(bqkv + 3072);
    unsigned short* qkvb   = region;                                // 4096*3072
    unsigned short* hb     = region + (size_t)4096 * 3072;          // 4096*1024 (LN1 out)
    unsigned short* vtb    = hb;                                    // 32*64*2048 (hb dead after QKV gemm)
    unsigned short* a1     = region;                                // 4096*4096 (qkv+vt dead after attn)
    unsigned short* attn_o = region + (size_t)4096 * 4096;          // 4096*1024
    unsigned short* h2     = attn_o;                                // alias (attn_o dead when written)
    float*          out1   = (float*)(attn_o + (size_t)4096 * 1024);// 4096*1024 fp32
    float*          outf   = (float*)d_out;

    dim3 blk(256);

    cvt_kernel<<<1024, blk, 0, stream>>>(wq, wqkv_b, 1024 * 1024);
    cvt_kernel<<<1024, blk, 0, stream>>>(wk, wqkv_b + 1024 * 1024, 1024 * 1024);
    cvt_kernel<<<1024, blk, 0, stream>>>(wv, wqkv_b + 2 * 1024 * 1024, 1024 * 1024);
    cvt_kernel<<<1024, blk, 0, stream>>>(wo, wo_b, 1024 * 1024);
    cvt_kernel<<<4096, blk, 0, stream>>>(w1, w1_b, 4096 * 1024);
    cvt_kernel<<<4096, blk, 0, stream>>>(w2, w2_b, 4096 * 1024);
    concat3_kernel<<<12, blk, 0, stream>>>(bq, bk, bvv, bqkv);

    ln_kernel<<<MTOT, blk, 0, stream>>>(x, ln1_g, ln1_b, hb);

    // fused QKV gemm: (4096,1024) @ (3072,1024)^T ; grid 24x32 = 768 blocks
    gemm_kernel<false, false, true><<<768, blk, 0, stream>>>(
        hb, wqkv_b, bqkv, nullptr, qkvb, MTOT, 3072, FEATS, 24);

    vtrans_kernel<<<dim3(BATCH * NH, SEQ / 64), blk, 0, stream>>>(qkvb, vtb);

    attn_kernel<<<dim3(BATCH * NH, SEQ / 128), dim3(512), 0, stream>>>(qkvb, vtb, attn_o);

    // out proj + residual: grid 8x32 = 256 blocks
    gemm_kernel<false, true, false><<<256, blk, 0, stream>>>(
        attn_o, wo_b, bo, x, out1, MTOT, FEATS, FEATS, 8);

    ln_kernel<<<MTOT, blk, 0, stream>>>(out1, ln2_g, ln2_b, h2);

    // MLP1: grid 32x32 = 1024 blocks
    gemm_kernel<true, false, true><<<1024, blk, 0, stream>>>(
        h2, w1_b, b1, nullptr, a1, MTOT, MLPH, FEATS, 32);

    // MLP2: grid 8x32 = 256 blocks
    gemm_kernel<true, true, false><<<256, blk, 0, stream>>>(
        a1, w2_b, b2, out1, outf, MTOT, FEATS, MLPH, 8);
}